// Round 2
// baseline (378.711 us; speedup 1.0000x reference)
//
#include <hip/hip_runtime.h>

// ---------------------------------------------------------------------------
// DeformableTransformerEncoderLayer on MI355X (gfx950) — round 2
//   prep:   qb = bf16(src+pos), srcb = bf16(src)            (padded to M_PAD)
//   GEMM:   offa = qb @ [W_off|W_attn] + [b_off|b_attn]     (f32, N=384 fused)
//   GEMM:   valb = srcb @ W_val + b_val                     (bf16)
//   sample: outb = MSDeformAttn(offa, valb)                 (bf16)
//   GEMM:   src2 = outb @ W_out + b_out                     (f32)
//   LN1:    x = LN(src+src2), xb = bf16(x)
//   FFN (split halves, residual accumulated in-place into x):
//     hbh = relu(xb @ W1[:,h*512:+512] + b1h)   (bf16)
//     x  += hbh @ W2[h*512:+512,:]  (+b2 on first half)
//   LN2:    d_out = LN(x)
// GEMMs: bf16 MFMA 16x16x32, global_load_lds(16B) staging (m97 structure).
// ---------------------------------------------------------------------------

typedef __bf16 bf16x8 __attribute__((ext_vector_type(8)));
typedef __bf16 bf16x4 __attribute__((ext_vector_type(4)));
typedef float floatx4 __attribute__((ext_vector_type(4)));

#define S_TOTAL 13294
#define M_ROWS  26588      // 2 * 13294
#define M_PAD   26624      // 208 * 128
#define DMODEL  256

// async global->LDS, 16 bytes per lane; LDS dest is wave-uniform-base + lane*16
#define GLDS(g, l)                                                            \
    __builtin_amdgcn_global_load_lds(                                         \
        (const __attribute__((address_space(1))) void*)(g),                   \
        (__attribute__((address_space(3))) void*)(l), 16, 0, 0)

// ---------------- weight convert: W (K x N) f32 -> WT (N x K) bf16 ----------
__global__ __launch_bounds__(256) void convert_wt(const float* __restrict__ W,
                                                  __bf16* __restrict__ WT,
                                                  int K, int N) {
    int i = blockIdx.x * 256 + threadIdx.x;
    if (i >= N * K) return;
    int n = i / K, k = i - n * K;
    WT[i] = (__bf16)W[(size_t)k * N + n];
}

// ---------------- concat bias [b_off | b_attn] -----------------------------
__global__ __launch_bounds__(256) void concat_bias(const float* __restrict__ b0,
                                                   const float* __restrict__ b1,
                                                   float* __restrict__ bc) {
    int i = blockIdx.x * 256 + threadIdx.x;
    if (i < 256) bc[i] = b0[i];
    else if (i < 384) bc[i] = b1[i - 256];
}

// ---------------- prep: qb = bf16(src+pos), srcb = bf16(src), zero-pad ------
__global__ __launch_bounds__(256) void prep_k(const float* __restrict__ src,
                                              const float* __restrict__ pos,
                                              __bf16* __restrict__ qb,
                                              __bf16* __restrict__ srcb) {
    int i = blockIdx.x * 256 + threadIdx.x;   // over M_PAD*256
    if (i < M_ROWS * DMODEL) {
        float s = src[i];
        qb[i]   = (__bf16)(s + pos[i]);
        srcb[i] = (__bf16)s;
    } else {
        qb[i]   = (__bf16)0.f;
        srcb[i] = (__bf16)0.f;
    }
}

// ---------------- 128x128 tile bf16 MFMA GEMM (global_load_lds staging) ----
// A: (M_PAD x K) bf16 row-major, lda == K.
// BT: (N x Kfull) bf16 row-major with row stride ldb (>= K); uses K cols.
// C = A@B [+ bias] [+ Cf(in-place)] , optional relu, f32 or bf16 out.
template <bool RELU, bool BF16OUT, bool ACCUM>
__global__ __launch_bounds__(256, 2) void gemm128(const __bf16* __restrict__ A,
                                                  const __bf16* __restrict__ BT,
                                                  const float* __restrict__ bias,
                                                  float* __restrict__ Cf,
                                                  __bf16* __restrict__ Cb,
                                                  int N, int K, int ldb) {
    __shared__ __align__(16) __bf16 As[128 * 32];
    __shared__ __align__(16) __bf16 Bs[128 * 32];
    const int tid  = threadIdx.x;
    const int bm   = blockIdx.y, bn = blockIdx.x;
    const int wave = tid >> 6, lane = tid & 63;
    const int wr   = wave >> 1, wc = wave & 1;
    const int l16  = lane & 15, quad = lane >> 4;

    floatx4 acc[4][4] = {};

    const int lr = tid >> 2;           // staged row 0..63 (per half)
    const int lc = (tid & 3) * 8;      // element offset (16B chunks)
    const __bf16* Ag0 = A  + (size_t)(bm * 128 + lr) * K + lc;
    const __bf16* Ag1 = Ag0 + (size_t)64 * K;
    const __bf16* Bg0 = BT + (size_t)(bn * 128 + lr) * ldb + lc;
    const __bf16* Bg1 = Bg0 + (size_t)64 * ldb;
    __bf16* Al0 = As + tid * 8;
    __bf16* Al1 = As + 64 * 32 + tid * 8;
    __bf16* Bl0 = Bs + tid * 8;
    __bf16* Bl1 = Bs + 64 * 32 + tid * 8;

    for (int k0 = 0; k0 < K; k0 += 32) {
        __syncthreads();               // prior iter's LDS reads done
        GLDS(Ag0 + k0, Al0);
        GLDS(Ag1 + k0, Al1);
        GLDS(Bg0 + k0, Bl0);
        GLDS(Bg1 + k0, Bl1);
        __syncthreads();               // DMA complete (vmcnt drained @barrier)
        bf16x8 af[4], bf[4];
#pragma unroll
        for (int i = 0; i < 4; i++)
            af[i] = *(const bf16x8*)(As + (wr * 64 + i * 16 + l16) * 32 + quad * 8);
#pragma unroll
        for (int j = 0; j < 4; j++)
            bf[j] = *(const bf16x8*)(Bs + (wc * 64 + j * 16 + l16) * 32 + quad * 8);
#pragma unroll
        for (int i = 0; i < 4; i++)
#pragma unroll
            for (int j = 0; j < 4; j++)
                acc[i][j] = __builtin_amdgcn_mfma_f32_16x16x32_bf16(
                    af[i], bf[j], acc[i][j], 0, 0, 0);
    }

    const int row0 = bm * 128 + wr * 64;
    const int col0 = bn * 128 + wc * 64;
#pragma unroll
    for (int j = 0; j < 4; j++) {
        int   n  = col0 + j * 16 + l16;
        float bv = bias ? bias[n] : 0.f;
#pragma unroll
        for (int i = 0; i < 4; i++) {
            int m = row0 + i * 16 + quad * 4;
#pragma unroll
            for (int r = 0; r < 4; r++) {
                float v = acc[i][j][r] + bv;
                if (ACCUM) v += Cf[(size_t)(m + r) * N + n];
                if (RELU)  v = v > 0.f ? v : 0.f;
                if (BF16OUT) Cb[(size_t)(m + r) * N + n] = (__bf16)v;
                else         Cf[(size_t)(m + r) * N + n] = v;
            }
        }
    }
}

// ---------------- MSDeformAttn sampling ------------------------------------
// one block per padded row r; 8 heads x 4 levels x 4 points
// offa: (M_PAD x 384) f32 = [off(256) | attn_logits(128)]
__global__ __launch_bounds__(256) void sample_k(const float* __restrict__ offa,
                                                const __bf16* __restrict__ valb,
                                                const float* __restrict__ refp,
                                                __bf16* __restrict__ outb) {
    const int r   = blockIdx.x;
    const int tid = threadIdx.x;
    if (r >= M_ROWS) {                       // zero the padded rows
        outb[(size_t)r * 256 + tid] = (__bf16)0.f;
        return;
    }
    __shared__ float s_log[128];
    __shared__ int   s_row[128][4];
    __shared__ float s_w[128][4];

    const int n = (r >= S_TOTAL) ? 1 : 0;

    if (tid < 128) s_log[tid] = offa[(size_t)r * 384 + 256 + tid];
    __syncthreads();

    if (tid < 128) {
        const int HL[4] = {100, 50, 25, 13};
        const int ST[4] = {0, 10000, 12500, 13125};
        int h = tid >> 4, lp = tid & 15, l = lp >> 2;
        float mx = -1e30f;
        for (int i = 0; i < 16; i++) mx = fmaxf(mx, s_log[h * 16 + i]);
        float sum = 0.f;
        for (int i = 0; i < 16; i++) sum += __expf(s_log[h * 16 + i] - mx);
        float aw = __expf(s_log[tid] - mx) / sum;

        float ox = offa[(size_t)r * 384 + tid * 2];
        float oy = offa[(size_t)r * 384 + tid * 2 + 1];
        float rx = refp[((size_t)r * 4 + l) * 2];
        float ry = refp[((size_t)r * 4 + l) * 2 + 1];
        int   Wl = HL[l], Hl = HL[l];
        float x = rx * (float)Wl + ox - 0.5f;
        float y = ry * (float)Hl + oy - 0.5f;
        float xf = floorf(x), yf = floorf(y);
        float wx1 = x - xf, wy1 = y - yf;
        float wx0 = 1.f - wx1, wy0 = 1.f - wy1;
        int x0 = (int)xf, y0 = (int)yf;
        int base = n * S_TOTAL + ST[l];
#pragma unroll
        for (int c = 0; c < 4; c++) {
            int yy = y0 + (c >> 1), xx = x0 + (c & 1);
            bool valid = (yy >= 0) & (yy < Hl) & (xx >= 0) & (xx < Wl);
            int yc = min(max(yy, 0), Hl - 1);
            int xc = min(max(xx, 0), Wl - 1);
            float w = ((c >> 1) ? wy1 : wy0) * ((c & 1) ? wx1 : wx0);
            s_row[tid][c] = base + yc * Wl + xc;
            s_w[tid][c]   = valid ? w * aw : 0.f;
        }
    }
    __syncthreads();

    // phase 2: tid = h(3b) | pg(2b) | c(3b): 4 channels/lane, 4 points/lane,
    // 4-lane partial sums combined via shfl_xor(8) + shfl_xor(16)
    const int h  = tid >> 5;
    const int pg = (tid >> 3) & 3;
    const int c4 = (tid & 7) * 4;
    const __bf16* vb = valb + h * 32 + c4;
    float a0 = 0.f, a1 = 0.f, a2 = 0.f, a3 = 0.f;
#pragma unroll
    for (int p = 0; p < 4; p++) {
        int idx = h * 16 + pg * 4 + p;
#pragma unroll
        for (int c = 0; c < 4; c++) {
            float w  = s_w[idx][c];
            int   rr = s_row[idx][c];
            bf16x4 v = *(const bf16x4*)(vb + (size_t)rr * 256);
            a0 += w * (float)v[0];
            a1 += w * (float)v[1];
            a2 += w * (float)v[2];
            a3 += w * (float)v[3];
        }
    }
    a0 += __shfl_xor(a0, 8);  a0 += __shfl_xor(a0, 16);
    a1 += __shfl_xor(a1, 8);  a1 += __shfl_xor(a1, 16);
    a2 += __shfl_xor(a2, 8);  a2 += __shfl_xor(a2, 16);
    a3 += __shfl_xor(a3, 8);  a3 += __shfl_xor(a3, 16);
    if (pg == 0) {
        bf16x4 res = {(__bf16)a0, (__bf16)a1, (__bf16)a2, (__bf16)a3};
        *(bf16x4*)(outb + (size_t)r * 256 + h * 32 + c4) = res;
    }
}

// ---------------- LayerNorm kernels ----------------------------------------
// LN1: x = LN(src + src2) -> f32 x and bf16 xb (zero-padded rows)
__global__ __launch_bounds__(64) void ln1_k(const float* __restrict__ src,
                                            const float* __restrict__ src2,
                                            const float* __restrict__ g,
                                            const float* __restrict__ b,
                                            float* __restrict__ x,
                                            __bf16* __restrict__ xb) {
    const int r = blockIdx.x, lane = threadIdx.x;
    if (r >= M_ROWS) {
        bf16x4 z = {(__bf16)0.f, (__bf16)0.f, (__bf16)0.f, (__bf16)0.f};
        *(bf16x4*)(xb + (size_t)r * 256 + lane * 4) = z;
        return;
    }
    size_t base = (size_t)r * 256 + lane * 4;
    float4 a = *(const float4*)(src + base);
    float4 c = *(const float4*)(src2 + base);
    float v0 = a.x + c.x, v1 = a.y + c.y, v2 = a.z + c.z, v3 = a.w + c.w;
    float s  = v0 + v1 + v2 + v3;
    float sq = v0 * v0 + v1 * v1 + v2 * v2 + v3 * v3;
    for (int o = 32; o > 0; o >>= 1) {
        s  += __shfl_xor(s, o);
        sq += __shfl_xor(sq, o);
    }
    float mean = s * (1.f / 256.f);
    float var  = sq * (1.f / 256.f) - mean * mean;
    float rs   = rsqrtf(var + 1e-5f);
    float4 gg = *(const float4*)(g + lane * 4);
    float4 bb = *(const float4*)(b + lane * 4);
    float o0 = (v0 - mean) * rs * gg.x + bb.x;
    float o1 = (v1 - mean) * rs * gg.y + bb.y;
    float o2 = (v2 - mean) * rs * gg.z + bb.z;
    float o3 = (v3 - mean) * rs * gg.w + bb.w;
    *(float4*)(x + base) = make_float4(o0, o1, o2, o3);
    bf16x4 ob = {(__bf16)o0, (__bf16)o1, (__bf16)o2, (__bf16)o3};
    *(bf16x4*)(xb + base) = ob;
}

// LN2: out = LN(t)  (t already holds x + ffn, f32; valid rows only)
__global__ __launch_bounds__(64) void ln2_k(const float* __restrict__ t,
                                            const float* __restrict__ g,
                                            const float* __restrict__ b,
                                            float* __restrict__ out) {
    const int r = blockIdx.x, lane = threadIdx.x;
    size_t base = (size_t)r * 256 + lane * 4;
    float4 a = *(const float4*)(t + base);
    float v0 = a.x, v1 = a.y, v2 = a.z, v3 = a.w;
    float s  = v0 + v1 + v2 + v3;
    float sq = v0 * v0 + v1 * v1 + v2 * v2 + v3 * v3;
    for (int o = 32; o > 0; o >>= 1) {
        s  += __shfl_xor(s, o);
        sq += __shfl_xor(sq, o);
    }
    float mean = s * (1.f / 256.f);
    float var  = sq * (1.f / 256.f) - mean * mean;
    float rs   = rsqrtf(var + 1e-5f);
    float4 gg = *(const float4*)(g + lane * 4);
    float4 bb = *(const float4*)(b + lane * 4);
    float4 o4;
    o4.x = (v0 - mean) * rs * gg.x + bb.x;
    o4.y = (v1 - mean) * rs * gg.y + bb.y;
    o4.z = (v2 - mean) * rs * gg.z + bb.z;
    o4.w = (v3 - mean) * rs * gg.w + bb.w;
    *(float4*)(out + base) = o4;
}

// ---------------------------------------------------------------------------
extern "C" void kernel_launch(void* const* d_in, const int* in_sizes, int n_in,
                              void* d_out, int out_size, void* d_ws, size_t ws_size,
                              hipStream_t stream) {
    const float* src  = (const float*)d_in[0];
    const float* pos  = (const float*)d_in[1];
    const float* refp = (const float*)d_in[2];
    const float* W_off  = (const float*)d_in[5];
    const float* b_off  = (const float*)d_in[6];
    const float* W_attn = (const float*)d_in[7];
    const float* b_attn = (const float*)d_in[8];
    const float* W_val  = (const float*)d_in[9];
    const float* b_val  = (const float*)d_in[10];
    const float* W_out  = (const float*)d_in[11];
    const float* b_out  = (const float*)d_in[12];
    const float* W1     = (const float*)d_in[13];
    const float* b1     = (const float*)d_in[14];
    const float* W2     = (const float*)d_in[15];
    const float* b2     = (const float*)d_in[16];
    const float* g1     = (const float*)d_in[17];
    const float* beta1  = (const float*)d_in[18];
    const float* g2     = (const float*)d_in[19];
    const float* beta2  = (const float*)d_in[20];
    float* out = (float*)d_out;

    // ---- workspace layout (bytes); lifetimes verified per stage -----------
    const size_t RB = (size_t)M_PAD * 256 * 2;   // 13,631,488
    const size_t RF = (size_t)M_PAD * 256 * 4;   // 27,262,976
    char* ws = (char*)d_ws;
    __bf16* qb   = (__bf16*)(ws);                       //  0.0..13.6 MB
    __bf16* srcb = (__bf16*)(ws + RB);                  // 13.6..27.3
    float*  offa = (float*)(ws + 2 * RB);               // 27.3..68.2 (M_PAD x 384 f32)
    __bf16* valb = (__bf16*)(ws + 2 * RB + (size_t)M_PAD * 384 * 4);  // 68.2..81.8
    __bf16* outb = qb;                                  // qb dead after offa-GEMM
    float*  src2 = (float*)(ws + RB);                   // 13.6..40.9 (srcb+offa dead)
    float*  x    = (float*)(ws + RB + RF);              // 40.9..68.2 (offa tail)
    __bf16* xb   = qb;                                  // outb dead after out-GEMM
    __bf16* hbh  = (__bf16*)(ws + 2 * RB + (size_t)M_PAD * 384 * 4);  // 68.2..95.5 (valb dead; M_PAD x 512)
    char*   regW = ws + 2 * RB + (size_t)M_PAD * 384 * 4 + (size_t)M_PAD * 512 * 2;  // ~95.5 MB

    __bf16* WTcomb = (__bf16*)regW;                     // 384 x 256 (off rows then attn rows)
    __bf16* WTval  = (__bf16*)(regW + 196608);
    __bf16* WTout  = (__bf16*)(regW + 327680);
    __bf16* WT1    = (__bf16*)(regW + 458752);          // 1024 x 256
    __bf16* WT2    = (__bf16*)(regW + 983040);          // 256 x 1024
    float*  bc     = (float*)(regW + 1507328);          // 384

    auto cvt = [&](const float* W, __bf16* WT, int K, int N) {
        convert_wt<<<(N * K + 255) / 256, 256, 0, stream>>>(W, WT, K, N);
    };
    cvt(W_off, WTcomb, 256, 256);
    cvt(W_attn, WTcomb + 65536, 256, 128);
    cvt(W_val, WTval, 256, 256);
    cvt(W_out, WTout, 256, 256);
    cvt(W1, WT1, 256, 1024);
    cvt(W2, WT2, 1024, 256);
    concat_bias<<<2, 256, 0, stream>>>(b_off, b_attn, bc);

    prep_k<<<M_PAD, 256, 0, stream>>>(src, pos, qb, srcb);

    // fused off+attn projection (N=384) and value projection
    gemm128<false, false, false><<<dim3(3, M_PAD / 128), 256, 0, stream>>>(
        qb, WTcomb, bc, offa, nullptr, 384, 256, 256);
    gemm128<false, true, false><<<dim3(2, M_PAD / 128), 256, 0, stream>>>(
        srcb, WTval, b_val, nullptr, valb, 256, 256, 256);

    sample_k<<<M_PAD, 256, 0, stream>>>(offa, valb, refp, outb);

    gemm128<false, false, false><<<dim3(2, M_PAD / 128), 256, 0, stream>>>(
        outb, WTout, b_out, src2, nullptr, 256, 256, 256);
    ln1_k<<<M_PAD, 64, 0, stream>>>(src, src2, g1, beta1, x, xb);

    // FFN in two 512-wide halves; residual accumulated in-place into x
    for (int half = 0; half < 2; half++) {
        gemm128<true, true, false><<<dim3(4, M_PAD / 128), 256, 0, stream>>>(
            xb, WT1 + (size_t)half * 512 * 256, b1 + half * 512, nullptr, hbh,
            512, 256, 256);
        gemm128<false, false, true><<<dim3(2, M_PAD / 128), 256, 0, stream>>>(
            hbh, WT2 + half * 512, half == 0 ? b2 : nullptr, x, nullptr,
            256, 512, 1024);
    }
    ln2_k<<<M_ROWS, 64, 0, stream>>>(x, g2, beta2, out);
}

// Round 3
// 345.117 us; speedup vs baseline: 1.0973x; 1.0973x over previous
//
#include <hip/hip_runtime.h>

// ---------------------------------------------------------------------------
// DeformableTransformerEncoderLayer on MI355X (gfx950) — round 3
// Changes vs R2:
//  * gemm128 epilogue: per-wave LDS transpose -> coalesced 16B/8B stores
//    (R2 did 64 scalar stores/thread; 2-byte stores for bf16 outputs)
//  * sample_k: shfl softmax, bf16x8 gathers (8 loads/thread), ds_read_b64
//    paired (weight, byte-offset)
//  * single fused weight-convert kernel; float4 prep
// ---------------------------------------------------------------------------

typedef __bf16 bf16x8 __attribute__((ext_vector_type(8)));
typedef __bf16 bf16x4 __attribute__((ext_vector_type(4)));
typedef float floatx4 __attribute__((ext_vector_type(4)));

#define S_TOTAL 13294
#define M_ROWS  26588      // 2 * 13294
#define M_PAD   26624      // 208 * 128
#define DMODEL  256

#define GLDS(g, l)                                                            \
    __builtin_amdgcn_global_load_lds(                                         \
        (const __attribute__((address_space(1))) void*)(g),                   \
        (__attribute__((address_space(3))) void*)(l), 16, 0, 0)

// ---------------- fused weight conversion ----------------------------------
// WTcomb(384x256) | WTval(256x256) | WTout(256x256) | WT1(1024x256) |
// WT2(256x1024) | bc(384 f32)   -- all dst offsets fixed (elements)
struct CvtArgs {
    const float *Woff, *Wattn, *Wval, *Wout, *W1, *W2, *boff, *battn;
};
__global__ __launch_bounds__(256) void cvt_all(CvtArgs a, __bf16* __restrict__ wdst,
                                               float* __restrict__ bc) {
    int i = blockIdx.x * 256 + threadIdx.x;
    if (i < 65536) {                                  // W_off^T -> comb rows 0..255
        wdst[i] = (__bf16)a.Woff[(i & 255) * 256 + (i >> 8)];
    } else if (i < 98304) {                           // W_attn^T -> comb rows 256..383
        int j = i - 65536;
        wdst[i] = (__bf16)a.Wattn[(j & 255) * 128 + (j >> 8)];
    } else if (i < 163840) {                          // W_val^T
        int j = i - 98304;
        wdst[i] = (__bf16)a.Wval[(j & 255) * 256 + (j >> 8)];
    } else if (i < 229376) {                          // W_out^T
        int j = i - 163840;
        wdst[i] = (__bf16)a.Wout[(j & 255) * 256 + (j >> 8)];
    } else if (i < 491520) {                          // W1^T (1024x256)
        int j = i - 229376;
        wdst[i] = (__bf16)a.W1[(j & 255) * 1024 + (j >> 8)];
    } else if (i < 753664) {                          // W2^T (256x1024)
        int j = i - 491520;
        wdst[i] = (__bf16)a.W2[(j & 1023) * 256 + (j >> 10)];
    } else if (i < 754048) {                          // bias concat
        int j = i - 753664;
        bc[j] = (j < 256) ? a.boff[j] : a.battn[j - 256];
    }
}

// ---------------- prep: qb = bf16(src+pos), srcb = bf16(src), zero-pad ------
__global__ __launch_bounds__(256) void prep_k(const float* __restrict__ src,
                                              const float* __restrict__ pos,
                                              __bf16* __restrict__ qb,
                                              __bf16* __restrict__ srcb) {
    int i4 = blockIdx.x * 256 + threadIdx.x;          // over M_PAD*256/4
    size_t e = (size_t)i4 * 4;
    if (e < (size_t)M_ROWS * DMODEL) {
        float4 s = *(const float4*)(src + e);
        float4 p = *(const float4*)(pos + e);
        bf16x4 q = {(__bf16)(s.x + p.x), (__bf16)(s.y + p.y),
                    (__bf16)(s.z + p.z), (__bf16)(s.w + p.w)};
        bf16x4 sb = {(__bf16)s.x, (__bf16)s.y, (__bf16)s.z, (__bf16)s.w};
        *(bf16x4*)(qb + e)   = q;
        *(bf16x4*)(srcb + e) = sb;
    } else {
        bf16x4 z = {(__bf16)0.f, (__bf16)0.f, (__bf16)0.f, (__bf16)0.f};
        *(bf16x4*)(qb + e)   = z;
        *(bf16x4*)(srcb + e) = z;
    }
}

// ---------------- 128x128 tile bf16 MFMA GEMM ------------------------------
// A: (M_PAD x K) bf16 row-major (lda == K).
// BT: (N x Kfull) bf16 row-major, row stride ldb; uses K cols.
// C = A@B [+ bias] [+ Cf in-place] , optional relu, f32 or bf16 out.
// Epilogue: per-wave LDS transpose (64x16 f32, stride 20) -> coalesced stores.
template <bool RELU, bool BF16OUT, bool ACCUM>
__global__ __launch_bounds__(256, 2) void gemm128(const __bf16* __restrict__ A,
                                                  const __bf16* __restrict__ BT,
                                                  const float* __restrict__ bias,
                                                  float* __restrict__ Cf,
                                                  __bf16* __restrict__ Cb,
                                                  int N, int K, int ldb) {
    __shared__ __align__(16) char smem[20480];        // staging 16K / epilogue 20K
    __bf16* As = (__bf16*)smem;
    __bf16* Bs = (__bf16*)(smem + 8192);
    const int tid  = threadIdx.x;
    const int bm   = blockIdx.y, bn = blockIdx.x;
    const int wave = tid >> 6, lane = tid & 63;
    const int wr   = wave >> 1, wc = wave & 1;
    const int l16  = lane & 15, quad = lane >> 4;

    floatx4 acc[4][4] = {};

    const int lr = tid >> 2;           // staged row 0..63 (per half)
    const int lc = (tid & 3) * 8;      // element offset (16B chunks)
    const __bf16* Ag0 = A  + (size_t)(bm * 128 + lr) * K + lc;
    const __bf16* Ag1 = Ag0 + (size_t)64 * K;
    const __bf16* Bg0 = BT + (size_t)(bn * 128 + lr) * ldb + lc;
    const __bf16* Bg1 = Bg0 + (size_t)64 * ldb;
    __bf16* Al0 = As + tid * 8;
    __bf16* Al1 = As + 64 * 32 + tid * 8;
    __bf16* Bl0 = Bs + tid * 8;
    __bf16* Bl1 = Bs + 64 * 32 + tid * 8;

    for (int k0 = 0; k0 < K; k0 += 32) {
        __syncthreads();
        GLDS(Ag0 + k0, Al0);
        GLDS(Ag1 + k0, Al1);
        GLDS(Bg0 + k0, Bl0);
        GLDS(Bg1 + k0, Bl1);
        __syncthreads();
        bf16x8 af[4], bfr[4];
#pragma unroll
        for (int i = 0; i < 4; i++)
            af[i] = *(const bf16x8*)(As + (wr * 64 + i * 16 + l16) * 32 + quad * 8);
#pragma unroll
        for (int j = 0; j < 4; j++)
            bfr[j] = *(const bf16x8*)(Bs + (wc * 64 + j * 16 + l16) * 32 + quad * 8);
#pragma unroll
        for (int i = 0; i < 4; i++)
#pragma unroll
            for (int j = 0; j < 4; j++)
                acc[i][j] = __builtin_amdgcn_mfma_f32_16x16x32_bf16(
                    af[i], bfr[j], acc[i][j], 0, 0, 0);
    }

    __syncthreads();                   // staging LDS now reusable as patches
    float* patch = (float*)smem + wave * (64 * 20);   // 64 rows x 16 cols, stride 20
    const int row0 = bm * 128 + wr * 64;
    const int col0 = bn * 128 + wc * 64;
    const int plr = lane >> 2, plc = lane & 3;

#pragma unroll
    for (int j = 0; j < 4; j++) {
        int   n  = col0 + j * 16 + l16;
        float bv = bias ? bias[n] : 0.f;
#pragma unroll
        for (int i = 0; i < 4; i++)
#pragma unroll
            for (int r = 0; r < 4; r++) {
                float v = acc[i][j][r] + bv;
                if (RELU) v = fmaxf(v, 0.f);
                patch[(i * 16 + quad * 4 + r) * 20 + l16] = v;
            }
        // same-wave RAW on LDS: compiler inserts lgkmcnt wait; no barrier
#pragma unroll
        for (int rr = 0; rr < 4; rr++) {
            int row = rr * 16 + plr;
            float4 v4 = *(float4*)&patch[row * 20 + plc * 4];
            size_t gi = (size_t)(row0 + row) * N + col0 + j * 16 + plc * 4;
            if (BF16OUT) {
                bf16x4 ob = {(__bf16)v4.x, (__bf16)v4.y, (__bf16)v4.z, (__bf16)v4.w};
                *(bf16x4*)(Cb + gi) = ob;
            } else if (ACCUM) {
                float4 c4 = *(const float4*)(Cf + gi);
                v4.x += c4.x; v4.y += c4.y; v4.z += c4.z; v4.w += c4.w;
                *(float4*)(Cf + gi) = v4;
            } else {
                *(float4*)(Cf + gi) = v4;
            }
        }
    }
}

// ---------------- MSDeformAttn sampling ------------------------------------
// one block per padded row; offa: (M_PAD x 384) f32 = [off(256)|logits(128)]
__global__ __launch_bounds__(256) void sample_k(const float* __restrict__ offa,
                                                const __bf16* __restrict__ valb,
                                                const float* __restrict__ refp,
                                                __bf16* __restrict__ outb) {
    const int r   = blockIdx.x;
    const int tid = threadIdx.x;
    if (r >= M_ROWS) {
        outb[(size_t)r * 256 + tid] = (__bf16)0.f;
        return;
    }
    __shared__ float2 s_wo[128][4];    // {weight, byte-offset bits}
    const int n = (r >= S_TOTAL) ? 1 : 0;

    if (tid < 128) {
        const int HLc[4] = {100, 50, 25, 13};
        const int STc[4] = {0, 10000, 12500, 13125};
        int lp = tid & 15, l = lp >> 2;
        float logit = offa[(size_t)r * 384 + 256 + tid];
        // softmax across the 16 lanes of this head (heads = 16-lane groups)
        float mx = logit;
        mx = fmaxf(mx, __shfl_xor(mx, 1));
        mx = fmaxf(mx, __shfl_xor(mx, 2));
        mx = fmaxf(mx, __shfl_xor(mx, 4));
        mx = fmaxf(mx, __shfl_xor(mx, 8));
        float e = __expf(logit - mx);
        float s = e;
        s += __shfl_xor(s, 1); s += __shfl_xor(s, 2);
        s += __shfl_xor(s, 4); s += __shfl_xor(s, 8);
        float aw = e / s;

        float2 o2 = *(const float2*)(offa + (size_t)r * 384 + tid * 2);
        float rx = refp[((size_t)r * 4 + l) * 2];
        float ry = refp[((size_t)r * 4 + l) * 2 + 1];
        int   Wl = HLc[l];
        float x = rx * (float)Wl + o2.x - 0.5f;
        float y = ry * (float)Wl + o2.y - 0.5f;
        float xf = floorf(x), yf = floorf(y);
        float wx1 = x - xf, wy1 = y - yf;
        float wx0 = 1.f - wx1, wy0 = 1.f - wy1;
        int x0 = (int)xf, y0 = (int)yf;
        int base = n * S_TOTAL + STc[l];
#pragma unroll
        for (int c = 0; c < 4; c++) {
            int yy = y0 + (c >> 1), xx = x0 + (c & 1);
            bool valid = (yy >= 0) & (yy < Wl) & (xx >= 0) & (xx < Wl);
            int yc = min(max(yy, 0), Wl - 1);
            int xc = min(max(xx, 0), Wl - 1);
            float w = ((c >> 1) ? wy1 : wy0) * ((c & 1) ? wx1 : wx0);
            int off = (base + yc * Wl + xc) * 512;     // byte offset into valb
            s_wo[tid][c] = make_float2(valid ? w * aw : 0.f, __int_as_float(off));
        }
    }
    __syncthreads();

    // phase 2: tid = h(3) | pg(3) | cg(2): 8 channels/lane (bf16x8, 16B),
    // 2 points/lane, reduce 8 point-groups via shfl_xor 4/8/16
    const int h  = tid >> 5;
    const int pg = (tid >> 2) & 7;
    const int cg = tid & 3;
    const char* vbase = (const char*)valb + h * 64 + cg * 16;
    float a[8] = {};
#pragma unroll
    for (int pp = 0; pp < 2; pp++) {
        int idx = h * 16 + pg * 2 + pp;
#pragma unroll
        for (int c = 0; c < 4; c++) {
            float2 wo = s_wo[idx][c];
            float  w  = wo.x;
            bf16x8 v  = *(const bf16x8*)(vbase + __float_as_int(wo.y));
#pragma unroll
            for (int k = 0; k < 8; k++) a[k] += w * (float)v[k];
        }
    }
#pragma unroll
    for (int k = 0; k < 8; k++) {
        a[k] += __shfl_xor(a[k], 4);
        a[k] += __shfl_xor(a[k], 8);
        a[k] += __shfl_xor(a[k], 16);
    }
    if (pg == 0) {
        bf16x8 res;
#pragma unroll
        for (int k = 0; k < 8; k++) res[k] = (__bf16)a[k];
        *(bf16x8*)(outb + (size_t)r * 256 + h * 32 + cg * 8) = res;
    }
}

// ---------------- LayerNorm kernels ----------------------------------------
__global__ __launch_bounds__(64) void ln1_k(const float* __restrict__ src,
                                            const float* __restrict__ src2,
                                            const float* __restrict__ g,
                                            const float* __restrict__ b,
                                            float* __restrict__ x,
                                            __bf16* __restrict__ xb) {
    const int r = blockIdx.x, lane = threadIdx.x;
    if (r >= M_ROWS) {
        bf16x4 z = {(__bf16)0.f, (__bf16)0.f, (__bf16)0.f, (__bf16)0.f};
        *(bf16x4*)(xb + (size_t)r * 256 + lane * 4) = z;
        return;
    }
    size_t base = (size_t)r * 256 + lane * 4;
    float4 a = *(const float4*)(src + base);
    float4 c = *(const float4*)(src2 + base);
    float v0 = a.x + c.x, v1 = a.y + c.y, v2 = a.z + c.z, v3 = a.w + c.w;
    float s  = v0 + v1 + v2 + v3;
    float sq = v0 * v0 + v1 * v1 + v2 * v2 + v3 * v3;
    for (int o = 32; o > 0; o >>= 1) {
        s  += __shfl_xor(s, o);
        sq += __shfl_xor(sq, o);
    }
    float mean = s * (1.f / 256.f);
    float var  = sq * (1.f / 256.f) - mean * mean;
    float rs   = rsqrtf(var + 1e-5f);
    float4 gg = *(const float4*)(g + lane * 4);
    float4 bb = *(const float4*)(b + lane * 4);
    float o0 = (v0 - mean) * rs * gg.x + bb.x;
    float o1 = (v1 - mean) * rs * gg.y + bb.y;
    float o2 = (v2 - mean) * rs * gg.z + bb.z;
    float o3 = (v3 - mean) * rs * gg.w + bb.w;
    *(float4*)(x + base) = make_float4(o0, o1, o2, o3);
    bf16x4 ob = {(__bf16)o0, (__bf16)o1, (__bf16)o2, (__bf16)o3};
    *(bf16x4*)(xb + base) = ob;
}

__global__ __launch_bounds__(64) void ln2_k(const float* __restrict__ t,
                                            const float* __restrict__ g,
                                            const float* __restrict__ b,
                                            float* __restrict__ out) {
    const int r = blockIdx.x, lane = threadIdx.x;
    size_t base = (size_t)r * 256 + lane * 4;
    float4 a = *(const float4*)(t + base);
    float v0 = a.x, v1 = a.y, v2 = a.z, v3 = a.w;
    float s  = v0 + v1 + v2 + v3;
    float sq = v0 * v0 + v1 * v1 + v2 * v2 + v3 * v3;
    for (int o = 32; o > 0; o >>= 1) {
        s  += __shfl_xor(s, o);
        sq += __shfl_xor(sq, o);
    }
    float mean = s * (1.f / 256.f);
    float var  = sq * (1.f / 256.f) - mean * mean;
    float rs   = rsqrtf(var + 1e-5f);
    float4 gg = *(const float4*)(g + lane * 4);
    float4 bb = *(const float4*)(b + lane * 4);
    float4 o4;
    o4.x = (v0 - mean) * rs * gg.x + bb.x;
    o4.y = (v1 - mean) * rs * gg.y + bb.y;
    o4.z = (v2 - mean) * rs * gg.z + bb.z;
    o4.w = (v3 - mean) * rs * gg.w + bb.w;
    *(float4*)(out + base) = o4;
}

// ---------------------------------------------------------------------------
extern "C" void kernel_launch(void* const* d_in, const int* in_sizes, int n_in,
                              void* d_out, int out_size, void* d_ws, size_t ws_size,
                              hipStream_t stream) {
    const float* src  = (const float*)d_in[0];
    const float* pos  = (const float*)d_in[1];
    const float* refp = (const float*)d_in[2];
    const float* W_off  = (const float*)d_in[5];
    const float* b_off  = (const float*)d_in[6];
    const float* W_attn = (const float*)d_in[7];
    const float* b_attn = (const float*)d_in[8];
    const float* W_val  = (const float*)d_in[9];
    const float* b_val  = (const float*)d_in[10];
    const float* W_out  = (const float*)d_in[11];
    const float* b_out  = (const float*)d_in[12];
    const float* W1     = (const float*)d_in[13];
    const float* b1     = (const float*)d_in[14];
    const float* W2     = (const float*)d_in[15];
    const float* b2     = (const float*)d_in[16];
    const float* g1     = (const float*)d_in[17];
    const float* beta1  = (const float*)d_in[18];
    const float* g2     = (const float*)d_in[19];
    const float* beta2  = (const float*)d_in[20];
    float* out = (float*)d_out;

    // ---- workspace layout (proven-safe R2 aliasing, peak ~97 MB) ----------
    const size_t RB = (size_t)M_PAD * 256 * 2;   // 13,631,488
    const size_t RF = (size_t)M_PAD * 256 * 4;   // 27,262,976
    char* ws = (char*)d_ws;
    __bf16* qb   = (__bf16*)(ws);
    __bf16* srcb = (__bf16*)(ws + RB);
    float*  offa = (float*)(ws + 2 * RB);                              // M_PAD x 384
    __bf16* valb = (__bf16*)(ws + 2 * RB + (size_t)M_PAD * 384 * 4);
    __bf16* outb = qb;
    float*  src2 = (float*)(ws + RB);
    float*  x    = (float*)(ws + RB + RF);
    __bf16* xb   = qb;
    __bf16* hbh  = (__bf16*)(ws + 2 * RB + (size_t)M_PAD * 384 * 4);   // M_PAD x 512
    char*   regW = ws + 2 * RB + (size_t)M_PAD * 384 * 4 + (size_t)M_PAD * 512 * 2;

    __bf16* WTcomb = (__bf16*)regW;
    __bf16* WTval  = (__bf16*)(regW + 196608);
    __bf16* WTout  = (__bf16*)(regW + 327680);
    __bf16* WT1    = (__bf16*)(regW + 458752);
    __bf16* WT2    = (__bf16*)(regW + 983040);
    float*  bc     = (float*)(regW + 1507328);

    CvtArgs ca = {W_off, W_attn, W_val, W_out, W1, W2, b_off, b_attn};
    cvt_all<<<(754048 + 255) / 256, 256, 0, stream>>>(ca, WTcomb, bc);

    prep_k<<<M_PAD * 256 / 4 / 256, 256, 0, stream>>>(src, pos, qb, srcb);

    gemm128<false, false, false><<<dim3(3, M_PAD / 128), 256, 0, stream>>>(
        qb, WTcomb, bc, offa, nullptr, 384, 256, 256);
    gemm128<false, true, false><<<dim3(2, M_PAD / 128), 256, 0, stream>>>(
        srcb, WTval, b_val, nullptr, valb, 256, 256, 256);

    sample_k<<<M_PAD, 256, 0, stream>>>(offa, valb, refp, outb);

    gemm128<false, false, false><<<dim3(2, M_PAD / 128), 256, 0, stream>>>(
        outb, WTout, b_out, src2, nullptr, 256, 256, 256);
    ln1_k<<<M_PAD, 64, 0, stream>>>(src, src2, g1, beta1, x, xb);

    for (int half = 0; half < 2; half++) {
        gemm128<true, true, false><<<dim3(4, M_PAD / 128), 256, 0, stream>>>(
            xb, WT1 + (size_t)half * 512 * 256, b1 + half * 512, nullptr, hbh,
            512, 256, 256);
        gemm128<false, false, true><<<dim3(2, M_PAD / 128), 256, 0, stream>>>(
            hbh, WT2 + half * 512, half == 0 ? b2 : nullptr, x, nullptr,
            256, 512, 1024);
    }
    ln2_k<<<M_ROWS, 64, 0, stream>>>(x, g2, beta2, out);
}